// Round 14
// baseline (72.766 us; speedup 1.0000x reference)
//
#include <hip/hip_runtime.h>

#define NN 50000
#define NE 800000
#define NBKT 1563                    // coarse buckets (32 receivers each)
#define CAPB 768                     // slots per bucket (mean 512, max ~600)
#define SORTB 64                     // sort blocks inside fused
#define ECH (NE / SORTB)             // 12500 edges per sort block
#define GEMM_BLOCKS 782              // ceil(50000/64)
#define PREP_BLOCKS 72               // 64 Wt + 1 wa/ba + 7 cursor-init

typedef unsigned short ushort_t;
typedef __attribute__((ext_vector_type(8))) short short8;       // 8 bf16 MFMA frag
typedef __attribute__((ext_vector_type(8))) unsigned short u16x8;
typedef __attribute__((ext_vector_type(4))) float f32x4;

__device__ __forceinline__ ushort_t f2bf(float f) {
    unsigned u = __float_as_uint(f);
    unsigned r = (u + 0x7fffu + ((u >> 16) & 1u)) >> 16;   // RNE
    return (ushort_t)r;
}
__device__ __forceinline__ float bf_lo(unsigned u) { return __uint_as_float(u << 16); }
__device__ __forceinline__ float bf_hi(unsigned u) { return __uint_as_float(u & 0xffff0000u); }
__device__ __forceinline__ float lrelu(float v) { return (v > 0.f) ? v : 0.2f * v; }
// LDS XOR swizzle for 256B-stride rows (kills ds_read_b128 bank conflicts)
__device__ __forceinline__ int swz(int b) { return b ^ (((b >> 8) & 7) << 4); }

// ---- K0: prep — Wt bf16 transpose + folded logit vectors wa/ba + cursors ----
__global__ __launch_bounds__(256) void prep(
    const float* __restrict__ W, const float* __restrict__ bl,
    const float* __restrict__ alpha,
    ushort_t* __restrict__ Wt, float2* __restrict__ wa, float2* __restrict__ ba,
    int* __restrict__ cursor)
{
    int b = blockIdx.x;
    if (b < 64) {
        int idx = b * 256 + threadIdx.x;       // 16384 = 128*128
        int k = idx >> 7, n = idx & 127;
        Wt[n * 128 + k] = f2bf(W[k * 128 + n]);
    } else if (b == 64) {
        int t = threadIdx.x;
        if (t < 128) {
            float s0 = 0.f, s1 = 0.f;
            for (int n = 0; n < 64; ++n) {
                s0 += W[t * 128 + n] * alpha[n];
                s1 += W[t * 128 + 64 + n] * alpha[64 + n];
            }
            wa[t] = make_float2(s0, s1);       // logit_h = nodes · wa[:,h] + ba[h]
        } else if (t == 128) {
            float s0 = 0.f, s1 = 0.f;
            for (int n = 0; n < 64; ++n) {
                s0 += bl[n] * alpha[n];
                s1 += bl[64 + n] * alpha[64 + n];
            }
            *ba = make_float2(s0, s1);
        }
    } else {
        int i = (b - 65) * 256 + threadIdx.x;
        if (i < NBKT) cursor[i] = i * CAPB;    // bucket slot cursor = region base
    }
}

// ---- K1: fused [sort blocks: batched hist→claim→scatter] + [MFMA GEMM + a01]
__global__ __launch_bounds__(256) void fused(
    const float* __restrict__ A,      // nodes [NN][128] fp32
    const ushort_t* __restrict__ Wt_g,// bf16 W^T [128][128]
    const float* __restrict__ bl,     // [128]
    const float2* __restrict__ wa,    // [128]
    const float2* __restrict__ ba,    // [1]
    const int* __restrict__ snd,      // [NE]
    const int* __restrict__ rcv,      // [NE]
    ushort_t* __restrict__ Xb,        // bf16 [NN][128]
    float2* __restrict__ a01,         // [NN]
    int* __restrict__ cursor,         // [NBKT] bucket cursors (pre-seeded)
    unsigned* __restrict__ tmpB)      // [NBKT*CAPB] packed (rcv<<16)|snd
{
    __shared__ char lds[49152];
    const int bid = blockIdx.x;
    const int t = threadIdx.x;

    if (bid < SORTB) {
        // ---- bucket sort, all passes 8-batched for memory-level parallelism --
        int* hist = (int*)lds;                 // NBKT ints; becomes abs cursor
        for (int i = t; i < NBKT; i += 256) hist[i] = 0;
        __syncthreads();
        const int e0 = bid * ECH;
        // pass 1: histogram (8 loads in flight, then 8 LDS atomics)
        for (int base = 0; base < ECH; base += 8 * 256) {
            int r[8];
#pragma unroll
            for (int j = 0; j < 8; ++j) {
                int idx = base + j * 256 + t;
                r[j] = (idx < ECH) ? rcv[e0 + idx] : -1;
            }
#pragma unroll
            for (int j = 0; j < 8; ++j)
                if (r[j] >= 0) atomicAdd(&hist[r[j] >> 5], 1);
        }
        __syncthreads();
        // claim: 7 independent global atomics in flight per thread
        {
            int cval[7], cbase[7];
#pragma unroll
            for (int j = 0; j < 7; ++j) {
                int i = t + j * 256;
                cval[j] = (i < NBKT) ? hist[i] : 0;
            }
#pragma unroll
            for (int j = 0; j < 7; ++j) {
                int i = t + j * 256;
                cbase[j] = (i < NBKT && cval[j]) ? atomicAdd(&cursor[i], cval[j]) : 0;
            }
#pragma unroll
            for (int j = 0; j < 7; ++j) {
                int i = t + j * 256;
                if (i < NBKT) hist[i] = cbase[j];    // absolute base of claim
            }
        }
        __syncthreads();
        // pass 3: scatter (8 edge-loads in flight, then atomics, then stores)
        for (int base = 0; base < ECH; base += 8 * 256) {
            int r[8], s[8], pos[8];
            bool ok[8];
#pragma unroll
            for (int j = 0; j < 8; ++j) {
                int idx = base + j * 256 + t;
                ok[j] = (idx < ECH);
                r[j] = ok[j] ? rcv[e0 + idx] : 0;
                s[j] = ok[j] ? snd[e0 + idx] : 0;
            }
#pragma unroll
            for (int j = 0; j < 8; ++j)
                if (ok[j]) pos[j] = atomicAdd(&hist[r[j] >> 5], 1);
#pragma unroll
            for (int j = 0; j < 8; ++j)
                if (ok[j] && pos[j] < (r[j] >> 5) * CAPB + CAPB)   // overflow guard
                    tmpB[pos[j]] = ((unsigned)r[j] << 16) | (unsigned)s[j];
        }
        return;
    }

    // ---------------- MFMA GEMM: 64 node-rows x 128 channels ----------------
    const int r0 = (bid - SORTB) * 64;
    const int seg = t & 15;
    float2 wv[8];
#pragma unroll
    for (int j = 0; j < 8; ++j) wv[j] = wa[seg * 8 + j];
    const float2 bav = *ba;

#pragma unroll
    for (int it = 0; it < 4; ++it) {
        int row = it * 16 + (t >> 4);
        int r = r0 + row;
        float4 v0 = make_float4(0.f, 0.f, 0.f, 0.f), v1 = v0;
        if (r < NN) {
            v0 = *(const float4*)(A + (size_t)r * 128 + seg * 8);
            v1 = *(const float4*)(A + (size_t)r * 128 + seg * 8 + 4);
        }
        u16x8 p;
        p[0] = f2bf(v0.x); p[1] = f2bf(v0.y); p[2] = f2bf(v0.z); p[3] = f2bf(v0.w);
        p[4] = f2bf(v1.x); p[5] = f2bf(v1.y); p[6] = f2bf(v1.z); p[7] = f2bf(v1.w);
        *(u16x8*)(lds + swz(row * 256 + seg * 16)) = p;
        float p0 = v0.x * wv[0].x + v0.y * wv[1].x + v0.z * wv[2].x + v0.w * wv[3].x
                 + v1.x * wv[4].x + v1.y * wv[5].x + v1.z * wv[6].x + v1.w * wv[7].x;
        float p1 = v0.x * wv[0].y + v0.y * wv[1].y + v0.z * wv[2].y + v0.w * wv[3].y
                 + v1.x * wv[4].y + v1.y * wv[5].y + v1.z * wv[6].y + v1.w * wv[7].y;
#pragma unroll
        for (int d = 1; d < 16; d <<= 1) {
            p0 += __shfl_xor(p0, d);
            p1 += __shfl_xor(p1, d);
        }
        if (seg == 0 && r < NN)
            a01[r] = make_float2(lrelu(p0 + bav.x), lrelu(p1 + bav.y));
    }
#pragma unroll
    for (int it = 0; it < 8; ++it) {
        int id = it * 256 + t;
        int n = id >> 4, sg = id & 15;
        u16x8 p = *(const u16x8*)(Wt_g + n * 128 + sg * 8);
        *(u16x8*)(lds + swz(16384 + n * 256 + sg * 16)) = p;
    }
    __syncthreads();

    const int w = t >> 6, l = t & 63;
    const int lrow = l & 15, lk = l >> 4;
    f32x4 acc[8] = {f32x4{0,0,0,0}, f32x4{0,0,0,0}, f32x4{0,0,0,0}, f32x4{0,0,0,0},
                    f32x4{0,0,0,0}, f32x4{0,0,0,0}, f32x4{0,0,0,0}, f32x4{0,0,0,0}};
#pragma unroll
    for (int kc = 0; kc < 4; ++kc) {
        short8 bfrag = *(short8*)(lds + swz((w * 16 + lrow) * 256 + kc * 64 + lk * 16));
#pragma unroll
        for (int ct = 0; ct < 8; ++ct) {
            short8 afrag = *(short8*)(lds + swz(16384 + (ct * 16 + lrow) * 256 + kc * 64 + lk * 16));
            acc[ct] = __builtin_amdgcn_mfma_f32_16x16x32_bf16(afrag, bfrag, acc[ct], 0, 0, 0);
        }
    }
    const int r = r0 + w * 16 + lrow;
    if (r < NN) {
#pragma unroll
        for (int ct = 0; ct < 8; ++ct) {
            int c0 = ct * 16 + lk * 4;
            float4 b4 = *(const float4*)(bl + c0);
            ushort4 st;
            st.x = f2bf(acc[ct][0] + b4.x);
            st.y = f2bf(acc[ct][1] + b4.y);
            st.z = f2bf(acc[ct][2] + b4.z);
            st.w = f2bf(acc[ct][3] + b4.w);
            *(ushort4*)(Xb + (size_t)r * 128 + c0) = st;
        }
    }
}

// ---- K2: bucket_agg — scratch-free staging + 8-wide gather batches ----------
__global__ __launch_bounds__(256) void bucket_agg(
    const unsigned* __restrict__ tmpB, const int* __restrict__ cursor,
    const ushort_t* __restrict__ Xb, const float2* __restrict__ a01,
    const float* __restrict__ bias, float* __restrict__ out)
{
    __shared__ int cnt32[32], pre32[32], rkpos[32];
    __shared__ ushort_t lsnd[CAPB];
    __shared__ float2 lw[CAPB];

    const int b = blockIdx.x, t = threadIdx.x;
    const int base = b * CAPB;
    const int cnt = min(cursor[b] - base, CAPB);

    const int sg = t >> 4;          // subgroup 0..15
    const int l16 = t & 15;         // channel group: ch l16*8 .. +7
    const int head = l16 >> 2;
    const bool soft = (head < 2);

    // ---- staging: exactly 3 static slots/thread (CAPB = 3*256), no scratch ----
    if (t < 32) cnt32[t] = 0;
    __syncthreads();
    const bool v0 = (t < cnt), v1 = (t + 256 < cnt), v2 = (t + 512 < cnt);
    unsigned pk0 = v0 ? tmpB[base + t] : 0;            // 3 independent loads
    unsigned pk1 = v1 ? tmpB[base + t + 256] : 0;
    unsigned pk2 = v2 ? tmpB[base + t + 512] : 0;
    int sd0 = pk0 & 0xffff, sd1 = pk1 & 0xffff, sd2 = pk2 & 0xffff;
    float2 a0 = v0 ? a01[sd0] : make_float2(0.f, 0.f); // 3 independent gathers
    float2 a1 = v1 ? a01[sd1] : make_float2(0.f, 0.f);
    float2 a2 = v2 ? a01[sd2] : make_float2(0.f, 0.f);
    if (v0) atomicAdd(&cnt32[(pk0 >> 16) & 31], 1);
    if (v1) atomicAdd(&cnt32[(pk1 >> 16) & 31], 1);
    if (v2) atomicAdd(&cnt32[(pk2 >> 16) & 31], 1);
    __syncthreads();
    if (t < 32) {
        int v = cnt32[t], incl = v;
#pragma unroll
        for (int d = 1; d < 32; d <<= 1) {
            int u = __shfl_up(incl, d);
            if (t >= d) incl += u;
        }
        pre32[t] = incl - v;
        rkpos[t] = incl - v;
    }
    __syncthreads();
    if (v0) { int p = atomicAdd(&rkpos[(pk0 >> 16) & 31], 1);
              lsnd[p] = (ushort_t)sd0; lw[p] = make_float2(__expf(a0.x), __expf(a0.y)); }
    if (v1) { int p = atomicAdd(&rkpos[(pk1 >> 16) & 31], 1);
              lsnd[p] = (ushort_t)sd1; lw[p] = make_float2(__expf(a1.x), __expf(a1.y)); }
    if (v2) { int p = atomicAdd(&rkpos[(pk2 >> 16) & 31], 1);
              lsnd[p] = (ushort_t)sd2; lw[p] = make_float2(__expf(a2.x), __expf(a2.y)); }
    __syncthreads();

    float accA[8] = {0,0,0,0,0,0,0,0};   // node b*32+sg
    float accB[8] = {0,0,0,0,0,0,0,0};   // node b*32+sg+16
    float DA = 0.f, DB = 0.f;

    auto body = [&](float (&acc)[8], float& D, int j) {
        const int s0 = pre32[j], cn = cnt32[j];
        int i = 0;
        for (; i + 8 <= cn; i += 8) {          // 8 independent gathers in flight
            uint4 u[8]; float f[8];
#pragma unroll
            for (int q = 0; q < 8; ++q) {
                float2 w2 = lw[s0 + i + q];
                f[q] = soft ? ((head == 0) ? w2.x : w2.y) : 1.0f;
                int sd = lsnd[s0 + i + q];
                u[q] = *(const uint4*)(Xb + (size_t)sd * 128 + l16 * 8);
            }
#pragma unroll
            for (int q = 0; q < 8; ++q) {
                D += f[q];
                acc[0] = fmaf(f[q], bf_lo(u[q].x), acc[0]);
                acc[1] = fmaf(f[q], bf_hi(u[q].x), acc[1]);
                acc[2] = fmaf(f[q], bf_lo(u[q].y), acc[2]);
                acc[3] = fmaf(f[q], bf_hi(u[q].y), acc[3]);
                acc[4] = fmaf(f[q], bf_lo(u[q].z), acc[4]);
                acc[5] = fmaf(f[q], bf_hi(u[q].z), acc[5]);
                acc[6] = fmaf(f[q], bf_lo(u[q].w), acc[6]);
                acc[7] = fmaf(f[q], bf_hi(u[q].w), acc[7]);
            }
        }
        for (; i + 4 <= cn; i += 4) {          // 4-wide mid tail
            uint4 u[4]; float f[4];
#pragma unroll
            for (int q = 0; q < 4; ++q) {
                float2 w2 = lw[s0 + i + q];
                f[q] = soft ? ((head == 0) ? w2.x : w2.y) : 1.0f;
                int sd = lsnd[s0 + i + q];
                u[q] = *(const uint4*)(Xb + (size_t)sd * 128 + l16 * 8);
            }
#pragma unroll
            for (int q = 0; q < 4; ++q) {
                D += f[q];
                acc[0] = fmaf(f[q], bf_lo(u[q].x), acc[0]);
                acc[1] = fmaf(f[q], bf_hi(u[q].x), acc[1]);
                acc[2] = fmaf(f[q], bf_lo(u[q].y), acc[2]);
                acc[3] = fmaf(f[q], bf_hi(u[q].y), acc[3]);
                acc[4] = fmaf(f[q], bf_lo(u[q].z), acc[4]);
                acc[5] = fmaf(f[q], bf_hi(u[q].z), acc[5]);
                acc[6] = fmaf(f[q], bf_lo(u[q].w), acc[6]);
                acc[7] = fmaf(f[q], bf_hi(u[q].w), acc[7]);
            }
        }
        for (; i < cn; ++i) {                  // scalar tail
            float2 w2 = lw[s0 + i];
            int sd = lsnd[s0 + i];
            float f0 = soft ? ((head == 0) ? w2.x : w2.y) : 1.0f;
            D += f0;
            uint4 u0 = *(const uint4*)(Xb + (size_t)sd * 128 + l16 * 8);
            acc[0] = fmaf(f0, bf_lo(u0.x), acc[0]); acc[1] = fmaf(f0, bf_hi(u0.x), acc[1]);
            acc[2] = fmaf(f0, bf_lo(u0.y), acc[2]); acc[3] = fmaf(f0, bf_hi(u0.y), acc[3]);
            acc[4] = fmaf(f0, bf_lo(u0.z), acc[4]); acc[5] = fmaf(f0, bf_hi(u0.z), acc[5]);
            acc[6] = fmaf(f0, bf_lo(u0.w), acc[6]); acc[7] = fmaf(f0, bf_hi(u0.w), acc[7]);
        }
    };
    body(accA, DA, sg);
    body(accB, DB, sg + 16);

    // finalize: self loop + scale + bias + store
    auto fin = [&](float (&acc)[8], float& D, int j) {
        const int n = b * 32 + j;
        if (n >= NN) return;
        float2 a = a01[n];
        float w = soft ? ((head == 0) ? __expf(a.x) : __expf(a.y)) : 1.0f;
        D += w;
        uint4 u = *(const uint4*)(Xb + (size_t)n * 128 + l16 * 8);
        acc[0] = fmaf(w, bf_lo(u.x), acc[0]); acc[1] = fmaf(w, bf_hi(u.x), acc[1]);
        acc[2] = fmaf(w, bf_lo(u.y), acc[2]); acc[3] = fmaf(w, bf_hi(u.y), acc[3]);
        acc[4] = fmaf(w, bf_lo(u.z), acc[4]); acc[5] = fmaf(w, bf_hi(u.z), acc[5]);
        acc[6] = fmaf(w, bf_lo(u.w), acc[6]); acc[7] = fmaf(w, bf_hi(u.w), acc[7]);
        float scale = 1.0f / D;     // soft lanes: softmax denom; mean lanes: deg+1
        float4 b0 = *(const float4*)(bias + l16 * 8);
        float4 b1 = *(const float4*)(bias + l16 * 8 + 4);
        float4 o0 = make_float4(acc[0] * scale + b0.x, acc[1] * scale + b0.y,
                                acc[2] * scale + b0.z, acc[3] * scale + b0.w);
        float4 o1 = make_float4(acc[4] * scale + b1.x, acc[5] * scale + b1.y,
                                acc[6] * scale + b1.z, acc[7] * scale + b1.w);
        *(float4*)(out + (size_t)n * 128 + l16 * 8)     = o0;
        *(float4*)(out + (size_t)n * 128 + l16 * 8 + 4) = o1;
    };
    fin(accA, DA, sg);
    fin(accB, DB, sg + 16);
}

// ------------------------------------------------------------------------------
extern "C" void kernel_launch(void* const* d_in, const int* in_sizes, int n_in,
                              void* d_out, int out_size, void* d_ws, size_t ws_size,
                              hipStream_t stream)
{
    const float* nodes     = (const float*)d_in[0];
    const int*   senders   = (const int*)d_in[1];
    const int*   receivers = (const int*)d_in[2];
    const float* W         = (const float*)d_in[3];
    const float* b_lin     = (const float*)d_in[4];
    const float* alpha     = (const float*)d_in[5];
    const float* bias      = (const float*)d_in[6];
    float* out = (float*)d_out;

    char* ws = (char*)d_ws;
    ushort_t* Xb     = (ushort_t*)(ws);               // 12,800,000
    float2*   a01    = (float2*)  (ws + 12800000);    //    400,000
    ushort_t* Wt_g   = (ushort_t*)(ws + 13200000);    //     32,768
    float2*   wa     = (float2*)  (ws + 13232768);    //      1,024
    float2*   ba     = (float2*)  (ws + 13233792);    //         64
    int*      cursor = (int*)     (ws + 13233856);    //      6,252 (pad to 6,336)
    unsigned* tmpB   = (unsigned*)(ws + 13240192);    //  4,801,536 -> 18,041,728

    prep <<<PREP_BLOCKS, 256, 0, stream>>>(W, b_lin, alpha, Wt_g, wa, ba, cursor);
    fused<<<SORTB + GEMM_BLOCKS, 256, 0, stream>>>(
        nodes, Wt_g, b_lin, wa, ba, senders, receivers, Xb, a01, cursor, tmpB);
    bucket_agg<<<NBKT, 256, 0, stream>>>(tmpB, cursor, Xb, a01, bias, out);
}

// Round 15
// 67.551 us; speedup vs baseline: 1.0772x; 1.0772x over previous
//
#include <hip/hip_runtime.h>

#define NN 50000
#define NE 800000
#define NBKT 1563                    // coarse buckets (32 receivers each)
#define CAPB 768                     // slots per bucket (mean 512, max ~600)
#define SORTB 64                     // sort blocks inside fused
#define ECH (NE / SORTB)             // 12500 edges per sort block
#define GEMM_BLOCKS 782              // ceil(50000/64)
#define PREP_BLOCKS 72               // 64 Wt + 1 wa/ba + 7 cursor-init

typedef unsigned short ushort_t;
typedef __attribute__((ext_vector_type(8))) short short8;       // 8 bf16 MFMA frag
typedef __attribute__((ext_vector_type(8))) unsigned short u16x8;
typedef __attribute__((ext_vector_type(4))) float f32x4;

__device__ __forceinline__ ushort_t f2bf(float f) {
    unsigned u = __float_as_uint(f);
    unsigned r = (u + 0x7fffu + ((u >> 16) & 1u)) >> 16;   // RNE
    return (ushort_t)r;
}
__device__ __forceinline__ float bf_lo(unsigned u) { return __uint_as_float(u << 16); }
__device__ __forceinline__ float bf_hi(unsigned u) { return __uint_as_float(u & 0xffff0000u); }
__device__ __forceinline__ float lrelu(float v) { return (v > 0.f) ? v : 0.2f * v; }
// LDS XOR swizzle for 256B-stride rows (kills ds_read_b128 bank conflicts)
__device__ __forceinline__ int swz(int b) { return b ^ (((b >> 8) & 7) << 4); }

// ---- K0: prep — Wt bf16 transpose + folded logit vectors wa/ba + cursors ----
__global__ __launch_bounds__(256) void prep(
    const float* __restrict__ W, const float* __restrict__ bl,
    const float* __restrict__ alpha,
    ushort_t* __restrict__ Wt, float2* __restrict__ wa, float2* __restrict__ ba,
    int* __restrict__ cursor)
{
    int b = blockIdx.x;
    if (b < 64) {
        int idx = b * 256 + threadIdx.x;       // 16384 = 128*128
        int k = idx >> 7, n = idx & 127;
        Wt[n * 128 + k] = f2bf(W[k * 128 + n]);
    } else if (b == 64) {
        int t = threadIdx.x;
        if (t < 128) {
            float s0 = 0.f, s1 = 0.f;
            for (int n = 0; n < 64; ++n) {
                s0 += W[t * 128 + n] * alpha[n];
                s1 += W[t * 128 + 64 + n] * alpha[64 + n];
            }
            wa[t] = make_float2(s0, s1);       // logit_h = nodes · wa[:,h] + ba[h]
        } else if (t == 128) {
            float s0 = 0.f, s1 = 0.f;
            for (int n = 0; n < 64; ++n) {
                s0 += bl[n] * alpha[n];
                s1 += bl[64 + n] * alpha[64 + n];
            }
            *ba = make_float2(s0, s1);
        }
    } else {
        int i = (b - 65) * 256 + threadIdx.x;
        if (i < NBKT) cursor[i] = i * CAPB;    // bucket slot cursor = region base
    }
}

// ---- K1: fused [sort blocks: batched hist→claim→scatter] + [MFMA GEMM + a01]
__global__ __launch_bounds__(256) void fused(
    const float* __restrict__ A,      // nodes [NN][128] fp32
    const ushort_t* __restrict__ Wt_g,// bf16 W^T [128][128]
    const float* __restrict__ bl,     // [128]
    const float2* __restrict__ wa,    // [128]
    const float2* __restrict__ ba,    // [1]
    const int* __restrict__ snd,      // [NE]
    const int* __restrict__ rcv,      // [NE]
    ushort_t* __restrict__ Xb,        // bf16 [NN][128]
    float2* __restrict__ a01,         // [NN]
    int* __restrict__ cursor,         // [NBKT] bucket cursors (pre-seeded)
    unsigned* __restrict__ tmpB)      // [NBKT*CAPB] packed (rcv<<16)|snd
{
    __shared__ char lds[49152];
    const int bid = blockIdx.x;
    const int t = threadIdx.x;

    if (bid < SORTB) {
        // ---- bucket sort, all passes 8-batched for memory-level parallelism --
        int* hist = (int*)lds;                 // NBKT ints; becomes abs cursor
        for (int i = t; i < NBKT; i += 256) hist[i] = 0;
        __syncthreads();
        const int e0 = bid * ECH;
        // pass 1: histogram (8 loads in flight, then 8 LDS atomics)
        for (int base = 0; base < ECH; base += 8 * 256) {
            int r[8];
#pragma unroll
            for (int j = 0; j < 8; ++j) {
                int idx = base + j * 256 + t;
                r[j] = (idx < ECH) ? rcv[e0 + idx] : -1;
            }
#pragma unroll
            for (int j = 0; j < 8; ++j)
                if (r[j] >= 0) atomicAdd(&hist[r[j] >> 5], 1);
        }
        __syncthreads();
        // claim: 7 independent global atomics in flight per thread
        {
            int cval[7], cbase[7];
#pragma unroll
            for (int j = 0; j < 7; ++j) {
                int i = t + j * 256;
                cval[j] = (i < NBKT) ? hist[i] : 0;
            }
#pragma unroll
            for (int j = 0; j < 7; ++j) {
                int i = t + j * 256;
                cbase[j] = (i < NBKT && cval[j]) ? atomicAdd(&cursor[i], cval[j]) : 0;
            }
#pragma unroll
            for (int j = 0; j < 7; ++j) {
                int i = t + j * 256;
                if (i < NBKT) hist[i] = cbase[j];    // absolute base of claim
            }
        }
        __syncthreads();
        // pass 3: scatter (8 edge-loads in flight, then atomics, then stores)
        for (int base = 0; base < ECH; base += 8 * 256) {
            int r[8], s[8], pos[8];
            bool ok[8];
#pragma unroll
            for (int j = 0; j < 8; ++j) {
                int idx = base + j * 256 + t;
                ok[j] = (idx < ECH);
                r[j] = ok[j] ? rcv[e0 + idx] : 0;
                s[j] = ok[j] ? snd[e0 + idx] : 0;
            }
#pragma unroll
            for (int j = 0; j < 8; ++j)
                if (ok[j]) pos[j] = atomicAdd(&hist[r[j] >> 5], 1);
#pragma unroll
            for (int j = 0; j < 8; ++j)
                if (ok[j] && pos[j] < (r[j] >> 5) * CAPB + CAPB)   // overflow guard
                    tmpB[pos[j]] = ((unsigned)r[j] << 16) | (unsigned)s[j];
        }
        return;
    }

    // ---------------- MFMA GEMM: 64 node-rows x 128 channels ----------------
    const int r0 = (bid - SORTB) * 64;
    const int seg = t & 15;
    float2 wv[8];
#pragma unroll
    for (int j = 0; j < 8; ++j) wv[j] = wa[seg * 8 + j];
    const float2 bav = *ba;

#pragma unroll
    for (int it = 0; it < 4; ++it) {
        int row = it * 16 + (t >> 4);
        int r = r0 + row;
        float4 v0 = make_float4(0.f, 0.f, 0.f, 0.f), v1 = v0;
        if (r < NN) {
            v0 = *(const float4*)(A + (size_t)r * 128 + seg * 8);
            v1 = *(const float4*)(A + (size_t)r * 128 + seg * 8 + 4);
        }
        u16x8 p;
        p[0] = f2bf(v0.x); p[1] = f2bf(v0.y); p[2] = f2bf(v0.z); p[3] = f2bf(v0.w);
        p[4] = f2bf(v1.x); p[5] = f2bf(v1.y); p[6] = f2bf(v1.z); p[7] = f2bf(v1.w);
        *(u16x8*)(lds + swz(row * 256 + seg * 16)) = p;
        float p0 = v0.x * wv[0].x + v0.y * wv[1].x + v0.z * wv[2].x + v0.w * wv[3].x
                 + v1.x * wv[4].x + v1.y * wv[5].x + v1.z * wv[6].x + v1.w * wv[7].x;
        float p1 = v0.x * wv[0].y + v0.y * wv[1].y + v0.z * wv[2].y + v0.w * wv[3].y
                 + v1.x * wv[4].y + v1.y * wv[5].y + v1.z * wv[6].y + v1.w * wv[7].y;
#pragma unroll
        for (int d = 1; d < 16; d <<= 1) {
            p0 += __shfl_xor(p0, d);
            p1 += __shfl_xor(p1, d);
        }
        if (seg == 0 && r < NN)
            a01[r] = make_float2(lrelu(p0 + bav.x), lrelu(p1 + bav.y));
    }
#pragma unroll
    for (int it = 0; it < 8; ++it) {
        int id = it * 256 + t;
        int n = id >> 4, sg = id & 15;
        u16x8 p = *(const u16x8*)(Wt_g + n * 128 + sg * 8);
        *(u16x8*)(lds + swz(16384 + n * 256 + sg * 16)) = p;
    }
    __syncthreads();

    const int w = t >> 6, l = t & 63;
    const int lrow = l & 15, lk = l >> 4;
    f32x4 acc[8] = {f32x4{0,0,0,0}, f32x4{0,0,0,0}, f32x4{0,0,0,0}, f32x4{0,0,0,0},
                    f32x4{0,0,0,0}, f32x4{0,0,0,0}, f32x4{0,0,0,0}, f32x4{0,0,0,0}};
#pragma unroll
    for (int kc = 0; kc < 4; ++kc) {
        short8 bfrag = *(short8*)(lds + swz((w * 16 + lrow) * 256 + kc * 64 + lk * 16));
#pragma unroll
        for (int ct = 0; ct < 8; ++ct) {
            short8 afrag = *(short8*)(lds + swz(16384 + (ct * 16 + lrow) * 256 + kc * 64 + lk * 16));
            acc[ct] = __builtin_amdgcn_mfma_f32_16x16x32_bf16(afrag, bfrag, acc[ct], 0, 0, 0);
        }
    }
    const int r = r0 + w * 16 + lrow;
    if (r < NN) {
#pragma unroll
        for (int ct = 0; ct < 8; ++ct) {
            int c0 = ct * 16 + lk * 4;
            float4 b4 = *(const float4*)(bl + c0);
            ushort4 st;
            st.x = f2bf(acc[ct][0] + b4.x);
            st.y = f2bf(acc[ct][1] + b4.y);
            st.z = f2bf(acc[ct][2] + b4.z);
            st.w = f2bf(acc[ct][3] + b4.w);
            *(ushort4*)(Xb + (size_t)r * 128 + c0) = st;
        }
    }
}

// ---- K2: bucket_agg — scratch-free staging + 4-wide gather batches ----------
__global__ __launch_bounds__(256) void bucket_agg(
    const unsigned* __restrict__ tmpB, const int* __restrict__ cursor,
    const ushort_t* __restrict__ Xb, const float2* __restrict__ a01,
    const float* __restrict__ bias, float* __restrict__ out)
{
    __shared__ int cnt32[32], pre32[32], rkpos[32];
    __shared__ ushort_t lsnd[CAPB];
    __shared__ float2 lw[CAPB];

    const int b = blockIdx.x, t = threadIdx.x;
    const int base = b * CAPB;
    const int cnt = min(cursor[b] - base, CAPB);

    const int sg = t >> 4;          // subgroup 0..15
    const int l16 = t & 15;         // channel group: ch l16*8 .. +7
    const int head = l16 >> 2;
    const bool soft = (head < 2);

    // ---- staging: exactly 3 static slots/thread (CAPB = 3*256), no scratch ----
    if (t < 32) cnt32[t] = 0;
    __syncthreads();
    const bool v0 = (t < cnt), v1 = (t + 256 < cnt), v2 = (t + 512 < cnt);
    unsigned pk0 = v0 ? tmpB[base + t] : 0;            // 3 independent loads
    unsigned pk1 = v1 ? tmpB[base + t + 256] : 0;
    unsigned pk2 = v2 ? tmpB[base + t + 512] : 0;
    int sd0 = pk0 & 0xffff, sd1 = pk1 & 0xffff, sd2 = pk2 & 0xffff;
    float2 a0 = v0 ? a01[sd0] : make_float2(0.f, 0.f); // 3 independent gathers
    float2 a1 = v1 ? a01[sd1] : make_float2(0.f, 0.f);
    float2 a2 = v2 ? a01[sd2] : make_float2(0.f, 0.f);
    if (v0) atomicAdd(&cnt32[(pk0 >> 16) & 31], 1);
    if (v1) atomicAdd(&cnt32[(pk1 >> 16) & 31], 1);
    if (v2) atomicAdd(&cnt32[(pk2 >> 16) & 31], 1);
    __syncthreads();
    if (t < 32) {
        int v = cnt32[t], incl = v;
#pragma unroll
        for (int d = 1; d < 32; d <<= 1) {
            int u = __shfl_up(incl, d);
            if (t >= d) incl += u;
        }
        pre32[t] = incl - v;
        rkpos[t] = incl - v;
    }
    __syncthreads();
    if (v0) { int p = atomicAdd(&rkpos[(pk0 >> 16) & 31], 1);
              lsnd[p] = (ushort_t)sd0; lw[p] = make_float2(__expf(a0.x), __expf(a0.y)); }
    if (v1) { int p = atomicAdd(&rkpos[(pk1 >> 16) & 31], 1);
              lsnd[p] = (ushort_t)sd1; lw[p] = make_float2(__expf(a1.x), __expf(a1.y)); }
    if (v2) { int p = atomicAdd(&rkpos[(pk2 >> 16) & 31], 1);
              lsnd[p] = (ushort_t)sd2; lw[p] = make_float2(__expf(a2.x), __expf(a2.y)); }
    __syncthreads();

    float accA[8] = {0,0,0,0,0,0,0,0};   // node b*32+sg
    float accB[8] = {0,0,0,0,0,0,0,0};   // node b*32+sg+16
    float DA = 0.f, DB = 0.f;

    auto body = [&](float (&acc)[8], float& D, int j) {
        const int s0 = pre32[j], cn = cnt32[j];
        int i = 0;
        for (; i + 4 <= cn; i += 4) {           // 4 independent gathers in flight
            float2 wv0 = lw[s0 + i],     wv1 = lw[s0 + i + 1];
            float2 wv2 = lw[s0 + i + 2], wv3 = lw[s0 + i + 3];
            int sd0_ = lsnd[s0 + i],     sd1_ = lsnd[s0 + i + 1];
            int sd2_ = lsnd[s0 + i + 2], sd3_ = lsnd[s0 + i + 3];
            uint4 u0 = *(const uint4*)(Xb + (size_t)sd0_ * 128 + l16 * 8);
            uint4 u1 = *(const uint4*)(Xb + (size_t)sd1_ * 128 + l16 * 8);
            uint4 u2 = *(const uint4*)(Xb + (size_t)sd2_ * 128 + l16 * 8);
            uint4 u3 = *(const uint4*)(Xb + (size_t)sd3_ * 128 + l16 * 8);
            float f0 = soft ? ((head == 0) ? wv0.x : wv0.y) : 1.0f;
            float f1 = soft ? ((head == 0) ? wv1.x : wv1.y) : 1.0f;
            float f2 = soft ? ((head == 0) ? wv2.x : wv2.y) : 1.0f;
            float f3 = soft ? ((head == 0) ? wv3.x : wv3.y) : 1.0f;
            D += (f0 + f1) + (f2 + f3);
            acc[0] = fmaf(f0, bf_lo(u0.x), acc[0]); acc[1] = fmaf(f0, bf_hi(u0.x), acc[1]);
            acc[2] = fmaf(f0, bf_lo(u0.y), acc[2]); acc[3] = fmaf(f0, bf_hi(u0.y), acc[3]);
            acc[4] = fmaf(f0, bf_lo(u0.z), acc[4]); acc[5] = fmaf(f0, bf_hi(u0.z), acc[5]);
            acc[6] = fmaf(f0, bf_lo(u0.w), acc[6]); acc[7] = fmaf(f0, bf_hi(u0.w), acc[7]);
            acc[0] = fmaf(f1, bf_lo(u1.x), acc[0]); acc[1] = fmaf(f1, bf_hi(u1.x), acc[1]);
            acc[2] = fmaf(f1, bf_lo(u1.y), acc[2]); acc[3] = fmaf(f1, bf_hi(u1.y), acc[3]);
            acc[4] = fmaf(f1, bf_lo(u1.z), acc[4]); acc[5] = fmaf(f1, bf_hi(u1.z), acc[5]);
            acc[6] = fmaf(f1, bf_lo(u1.w), acc[6]); acc[7] = fmaf(f1, bf_hi(u1.w), acc[7]);
            acc[0] = fmaf(f2, bf_lo(u2.x), acc[0]); acc[1] = fmaf(f2, bf_hi(u2.x), acc[1]);
            acc[2] = fmaf(f2, bf_lo(u2.y), acc[2]); acc[3] = fmaf(f2, bf_hi(u2.y), acc[3]);
            acc[4] = fmaf(f2, bf_lo(u2.z), acc[4]); acc[5] = fmaf(f2, bf_hi(u2.z), acc[5]);
            acc[6] = fmaf(f2, bf_lo(u2.w), acc[6]); acc[7] = fmaf(f2, bf_hi(u2.w), acc[7]);
            acc[0] = fmaf(f3, bf_lo(u3.x), acc[0]); acc[1] = fmaf(f3, bf_hi(u3.x), acc[1]);
            acc[2] = fmaf(f3, bf_lo(u3.y), acc[2]); acc[3] = fmaf(f3, bf_hi(u3.y), acc[3]);
            acc[4] = fmaf(f3, bf_lo(u3.z), acc[4]); acc[5] = fmaf(f3, bf_hi(u3.z), acc[5]);
            acc[6] = fmaf(f3, bf_lo(u3.w), acc[6]); acc[7] = fmaf(f3, bf_hi(u3.w), acc[7]);
        }
        for (; i < cn; ++i) {
            float2 wv0 = lw[s0 + i];
            int sd0_ = lsnd[s0 + i];
            float f0 = soft ? ((head == 0) ? wv0.x : wv0.y) : 1.0f;
            D += f0;
            uint4 u0 = *(const uint4*)(Xb + (size_t)sd0_ * 128 + l16 * 8);
            acc[0] = fmaf(f0, bf_lo(u0.x), acc[0]); acc[1] = fmaf(f0, bf_hi(u0.x), acc[1]);
            acc[2] = fmaf(f0, bf_lo(u0.y), acc[2]); acc[3] = fmaf(f0, bf_hi(u0.y), acc[3]);
            acc[4] = fmaf(f0, bf_lo(u0.z), acc[4]); acc[5] = fmaf(f0, bf_hi(u0.z), acc[5]);
            acc[6] = fmaf(f0, bf_lo(u0.w), acc[6]); acc[7] = fmaf(f0, bf_hi(u0.w), acc[7]);
        }
    };
    body(accA, DA, sg);
    body(accB, DB, sg + 16);

    // finalize: self loop + scale + bias + store
    auto fin = [&](float (&acc)[8], float& D, int j) {
        const int n = b * 32 + j;
        if (n >= NN) return;
        float2 a = a01[n];
        float w = soft ? ((head == 0) ? __expf(a.x) : __expf(a.y)) : 1.0f;
        D += w;
        uint4 u = *(const uint4*)(Xb + (size_t)n * 128 + l16 * 8);
        acc[0] = fmaf(w, bf_lo(u.x), acc[0]); acc[1] = fmaf(w, bf_hi(u.x), acc[1]);
        acc[2] = fmaf(w, bf_lo(u.y), acc[2]); acc[3] = fmaf(w, bf_hi(u.y), acc[3]);
        acc[4] = fmaf(w, bf_lo(u.z), acc[4]); acc[5] = fmaf(w, bf_hi(u.z), acc[5]);
        acc[6] = fmaf(w, bf_lo(u.w), acc[6]); acc[7] = fmaf(w, bf_hi(u.w), acc[7]);
        float scale = 1.0f / D;     // soft lanes: softmax denom; mean lanes: deg+1
        float4 b0 = *(const float4*)(bias + l16 * 8);
        float4 b1 = *(const float4*)(bias + l16 * 8 + 4);
        float4 o0 = make_float4(acc[0] * scale + b0.x, acc[1] * scale + b0.y,
                                acc[2] * scale + b0.z, acc[3] * scale + b0.w);
        float4 o1 = make_float4(acc[4] * scale + b1.x, acc[5] * scale + b1.y,
                                acc[6] * scale + b1.z, acc[7] * scale + b1.w);
        *(float4*)(out + (size_t)n * 128 + l16 * 8)     = o0;
        *(float4*)(out + (size_t)n * 128 + l16 * 8 + 4) = o1;
    };
    fin(accA, DA, sg);
    fin(accB, DB, sg + 16);
}

// ------------------------------------------------------------------------------
extern "C" void kernel_launch(void* const* d_in, const int* in_sizes, int n_in,
                              void* d_out, int out_size, void* d_ws, size_t ws_size,
                              hipStream_t stream)
{
    const float* nodes     = (const float*)d_in[0];
    const int*   senders   = (const int*)d_in[1];
    const int*   receivers = (const int*)d_in[2];
    const float* W         = (const float*)d_in[3];
    const float* b_lin     = (const float*)d_in[4];
    const float* alpha     = (const float*)d_in[5];
    const float* bias      = (const float*)d_in[6];
    float* out = (float*)d_out;

    char* ws = (char*)d_ws;
    ushort_t* Xb     = (ushort_t*)(ws);               // 12,800,000
    float2*   a01    = (float2*)  (ws + 12800000);    //    400,000
    ushort_t* Wt_g   = (ushort_t*)(ws + 13200000);    //     32,768
    float2*   wa     = (float2*)  (ws + 13232768);    //      1,024
    float2*   ba     = (float2*)  (ws + 13233792);    //         64
    int*      cursor = (int*)     (ws + 13233856);    //      6,252 (pad to 6,336)
    unsigned* tmpB   = (unsigned*)(ws + 13240192);    //  4,801,536 -> 18,041,728

    prep <<<PREP_BLOCKS, 256, 0, stream>>>(W, b_lin, alpha, Wt_g, wa, ba, cursor);
    fused<<<SORTB + GEMM_BLOCKS, 256, 0, stream>>>(
        nodes, Wt_g, b_lin, wa, ba, senders, receivers, Xb, a01, cursor, tmpB);
    bucket_agg<<<NBKT, 256, 0, stream>>>(tmpB, cursor, Xb, a01, bias, out);
}